// Round 4
// baseline (1371.997 us; speedup 1.0000x reference)
//
#include <hip/hip_runtime.h>
#include <hip/hip_bf16.h>

#define N_NODES 50000
#define N_EDGES 800000
#define D 128
#define N_ETYPES 4
#define N_STEPS 8
#define B_GRAPHS 50
#define HID 256
#define POOL_SPLIT 16
#define SCAN_B 196  // ceil(50000/256)

typedef __attribute__((ext_vector_type(8))) short short8;
typedef __attribute__((ext_vector_type(4))) float f32x4;
typedef __attribute__((ext_vector_type(4))) unsigned uint4v;

static __device__ __forceinline__ unsigned short f2bf(float f) {
    union { float f; unsigned u; } v; v.f = f;
    unsigned r = v.u + 0x7FFF + ((v.u >> 16) & 1);
    return (unsigned short)(r >> 16);
}
static __device__ __forceinline__ float bf2f_u(unsigned s) {  // low 16 bits
    union { unsigned u; float f; } v; v.u = s << 16;
    return v.f;
}
static __device__ __forceinline__ float fsigmoid(float x) {
    return 1.f / (1.f + __expf(-x));
}
static __device__ __forceinline__ float ftanh(float x) {
    return 2.f / (1.f + __expf(-2.f * x)) - 1.f;
}
static __device__ __forceinline__ void gload_lds16(const void* g, void* lds) {
    __builtin_amdgcn_global_load_lds(
        (const __attribute__((address_space(1))) unsigned char*)g,
        (__attribute__((address_space(3))) unsigned char*)lds, 16, 0, 0);
}

// ---------------- init: h_bf = bf16(node_features) ----------------
__global__ void k_init_h(const float* __restrict__ nf, unsigned short* __restrict__ hbf) {
    int i = blockIdx.x * blockDim.x + threadIdx.x;
    if (i < N_NODES * D) hbf[i] = f2bf(nf[i]);
}

// ---------------- CSR build ----------------
__global__ void k_hist(const int* __restrict__ dst, int* __restrict__ deg) {
    int e = blockIdx.x * blockDim.x + threadIdx.x;
    if (e < N_EDGES) atomicAdd(&deg[dst[e]], 1);
}

__global__ __launch_bounds__(256) void k_scan1(const int* __restrict__ deg,
                                               int* __restrict__ bsum) {
    __shared__ int tmp[256];
    int t = threadIdx.x;
    int i = blockIdx.x * 256 + t;
    tmp[t] = (i < N_NODES) ? deg[i] : 0;
    __syncthreads();
    for (int s = 128; s > 0; s >>= 1) {
        if (t < s) tmp[t] += tmp[t + s];
        __syncthreads();
    }
    if (t == 0) bsum[blockIdx.x] = tmp[0];
}

__global__ __launch_bounds__(256) void k_scan2(const int* __restrict__ bsum,
                                               int* __restrict__ bpfx,
                                               int* __restrict__ rowptr) {
    __shared__ int part[256];
    int t = threadIdx.x;
    int v = (t < SCAN_B) ? bsum[t] : 0;
    part[t] = v;
    __syncthreads();
    for (int off = 1; off < 256; off <<= 1) {
        int u = (t >= off) ? part[t - off] : 0;
        __syncthreads();
        part[t] += u;
        __syncthreads();
    }
    if (t < SCAN_B) bpfx[t] = part[t] - v;  // exclusive
    if (t == SCAN_B - 1) rowptr[N_NODES] = part[t];
}

__global__ __launch_bounds__(256) void k_scan3(const int* __restrict__ deg,
                                               const int* __restrict__ bpfx,
                                               int* __restrict__ rowptr,
                                               int* __restrict__ cursor) {
    __shared__ int part[256];
    int t = threadIdx.x;
    int i = blockIdx.x * 256 + t;
    int v = (i < N_NODES) ? deg[i] : 0;
    part[t] = v;
    __syncthreads();
    for (int off = 1; off < 256; off <<= 1) {
        int u = (t >= off) ? part[t - off] : 0;
        __syncthreads();
        part[t] += u;
        __syncthreads();
    }
    if (i < N_NODES) {
        int rp = bpfx[blockIdx.x] + part[t] - v;
        rowptr[i] = rp;
        cursor[i] = rp;
    }
}

__global__ void k_fill(const int* __restrict__ src, const int* __restrict__ dst,
                       const int* __restrict__ et, int* __restrict__ cursor,
                       int* __restrict__ epack) {
    int e = blockIdx.x * blockDim.x + threadIdx.x;
    if (e < N_EDGES) {
        int slot = atomicAdd(&cursor[dst[e]], 1);
        epack[slot] = src[e] | (et[e] << 16);  // src < 50000 < 2^16
    }
}

// ---------------- weight pre-pack into MFMA B-fragment layouts (bf16) --------
// Pmsg (Wstack, K=512, N=128): frag f = nt*16 + kc (nt<8, kc<16);
//   idx = (f*64 + l)*8 + i ; k = kc*32 + (l>>4)*8 + i ; n = nt*16 + (l&15)
// Pih/Phh (K=128, N=384): frag f = nt*4 + c ; k = c*32 + (l>>4)*8 + i ; B[k][n]=W[n][k]
__global__ void k_pack(const float* __restrict__ Wmsg, const float* __restrict__ Wih,
                       const float* __restrict__ Whh, unsigned short* __restrict__ Pmsg,
                       unsigned short* __restrict__ Pih, unsigned short* __restrict__ Phh) {
    int bt = blockIdx.x;  // 0..319
    int l = threadIdx.x;  // 0..63
    if (bt < 128) {  // Pmsg frag f = bt
        int nt = bt >> 4, kc = bt & 15;
        int n = nt * 16 + (l & 15);
        unsigned short* out = Pmsg + (((size_t)bt * 64 + l) * 8);
#pragma unroll
        for (int i = 0; i < 8; ++i) {
            int k = kc * 32 + ((l >> 4) << 3) + i;
            out[i] = f2bf(Wmsg[(size_t)(k >> 7) * (D * D) + (k & 127) * D + n]);
        }
        return;
    }
    const float* src;
    unsigned short* dstp;
    int id;
    if (bt < 224) { id = bt - 128; src = Wih; dstp = Pih; }
    else          { id = bt - 224; src = Whh; dstp = Phh; }
    int nt = id >> 2, c = id & 3;
    int n = nt * 16 + (l & 15);
    unsigned short* out = dstp + (((size_t)(nt * 4 + c) * 64 + l) * 8);
#pragma unroll
    for (int i = 0; i < 8; ++i) {
        int k = c * 32 + ((l >> 4) << 3) + i;
        out[i] = f2bf(src[n * D + k]);
    }
}

// ---------------- aggregate: S[v][t][d] = sum_{in-edges of type t} hbf[src][d] --
__global__ __launch_bounds__(256) void k_aggregate_s(const unsigned short* __restrict__ hbf,
                                                     const int* __restrict__ rowptr,
                                                     const int* __restrict__ epack,
                                                     unsigned short* __restrict__ S,
                                                     unsigned* __restrict__ deg4) {
    int w = threadIdx.x >> 6, l = threadIdx.x & 63;
    int v = blockIdx.x * 4 + w;
    if (v >= N_NODES) return;
    int lo = rowptr[v], hi = rowptr[v + 1];
    float a00 = 0.f, a01 = 0.f, a10 = 0.f, a11 = 0.f;
    float a20 = 0.f, a21 = 0.f, a30 = 0.f, a31 = 0.f;
    unsigned c0 = 0, c1 = 0, c2 = 0, c3 = 0;
    int i = lo;
    for (; i + 4 <= hi; i += 4) {
        int e0 = epack[i], e1 = epack[i + 1], e2 = epack[i + 2], e3 = epack[i + 3];
        unsigned x0 = *(const unsigned*)(hbf + ((size_t)(e0 & 0xFFFF) << 7) + 2 * l);
        unsigned x1 = *(const unsigned*)(hbf + ((size_t)(e1 & 0xFFFF) << 7) + 2 * l);
        unsigned x2 = *(const unsigned*)(hbf + ((size_t)(e2 & 0xFFFF) << 7) + 2 * l);
        unsigned x3 = *(const unsigned*)(hbf + ((size_t)(e3 & 0xFFFF) << 7) + 2 * l);
#define ACC_EDGE(e, x)                                                        \
        {                                                                     \
            int t_ = (e) >> 16;                                               \
            float lo_ = bf2f_u((x) & 0xFFFF), hi_ = bf2f_u((x) >> 16);        \
            if (t_ == 0)      { a00 += lo_; a01 += hi_; c0++; }               \
            else if (t_ == 1) { a10 += lo_; a11 += hi_; c1++; }               \
            else if (t_ == 2) { a20 += lo_; a21 += hi_; c2++; }               \
            else              { a30 += lo_; a31 += hi_; c3++; }               \
        }
        ACC_EDGE(e0, x0) ACC_EDGE(e1, x1) ACC_EDGE(e2, x2) ACC_EDGE(e3, x3)
    }
    for (; i < hi; ++i) {
        int e0 = epack[i];
        unsigned x0 = *(const unsigned*)(hbf + ((size_t)(e0 & 0xFFFF) << 7) + 2 * l);
        ACC_EDGE(e0, x0)
    }
#undef ACC_EDGE
    unsigned* Srow = (unsigned*)(S + (size_t)v * 512);
    Srow[l]       = (unsigned)f2bf(a00) | ((unsigned)f2bf(a01) << 16);
    Srow[64 + l]  = (unsigned)f2bf(a10) | ((unsigned)f2bf(a11) << 16);
    Srow[128 + l] = (unsigned)f2bf(a20) | ((unsigned)f2bf(a21) << 16);
    Srow[192 + l] = (unsigned)f2bf(a30) | ((unsigned)f2bf(a31) << 16);
    if (l == 0) {
        uint4v dg = {c0, c1, c2, c3};
        *(uint4v*)(deg4 + (size_t)v * 4) = dg;
    }
}

// ---------------- a-GEMM: abf[v] = bf16(S[v] @ Wstack + sum_t deg_t(v)*bmsg[t]) --
// block 64 rows (4 waves x 16); K=512; 2 passes x 4 ntiles, stage 64KB/pass
__global__ __launch_bounds__(256) void k_gemm_a(const unsigned short* __restrict__ S,
                                                const unsigned short* __restrict__ Pmsg,
                                                const unsigned* __restrict__ deg4,
                                                const float* __restrict__ bmsg,
                                                unsigned short* __restrict__ abf) {
    __shared__ unsigned short Bs[64 * 64 * 8];  // 64 KB
    int tid = threadIdx.x, w = tid >> 6, l = tid & 63;
    int base = blockIdx.x * 64 + w * 16;
    int lr = l & 15, kb = l >> 4;
    int arow_i = base + lr;
    if (arow_i >= N_NODES) arow_i = N_NODES - 1;
    const short8* arow = (const short8*)(S + (size_t)arow_i * 512);
    short8 af[16];
#pragma unroll
    for (int kc = 0; kc < 16; ++kc) af[kc] = arow[kc * 4 + kb];
    uint4v dg[4];
#pragma unroll
    for (int j = 0; j < 4; ++j) {
        int row = base + kb * 4 + j;
        if (row >= N_NODES) row = N_NODES - 1;
        dg[j] = *(const uint4v*)(deg4 + (size_t)row * 4);
    }
    for (int p = 0; p < 2; ++p) {
        __syncthreads();
#pragma unroll
        for (int j = 0; j < 16; ++j) {
            int ci = j * 4 + w;               // 0..63; global frag f = p*64 + ci
            gload_lds16(Pmsg + ((size_t)(p * 64 + ci) * 64 + l) * 8, Bs + (size_t)ci * 512);
        }
        __syncthreads();
        f32x4 acc[4] = {};
#pragma unroll
        for (int kc = 0; kc < 16; ++kc) {
#pragma unroll
            for (int ntl = 0; ntl < 4; ++ntl) {
                short8 b = *(const short8*)(Bs + ((ntl * 16 + kc) * 64 + l) * 8);
                acc[ntl] = __builtin_amdgcn_mfma_f32_16x16x32_bf16(af[kc], b, acc[ntl], 0, 0, 0);
            }
        }
#pragma unroll
        for (int ntl = 0; ntl < 4; ++ntl) {
            int col = (p * 4 + ntl) * 16 + lr;
            float b0 = bmsg[col], b1 = bmsg[128 + col], b2 = bmsg[256 + col], b3 = bmsg[384 + col];
#pragma unroll
            for (int j = 0; j < 4; ++j) {
                int row = base + kb * 4 + j;
                if (row < N_NODES) {
                    float bias = (float)dg[j].x * b0 + (float)dg[j].y * b1 +
                                 (float)dg[j].z * b2 + (float)dg[j].w * b3;
                    abf[(size_t)row * D + col] = f2bf(acc[ntl][j] + bias);
                }
            }
        }
    }
}

// ---------------- fused GRU (bf16 h): 3 phases, one gate per phase ----------
__global__ __launch_bounds__(256) void k_gru(const unsigned short* __restrict__ abf,
                                             unsigned short* __restrict__ hbf,
                                             const unsigned short* __restrict__ Pih,
                                             const unsigned short* __restrict__ Phh,
                                             const float* __restrict__ bih,
                                             const float* __restrict__ bhh) {
    __shared__ unsigned short Bs[64 * 64 * 8];  // 64 KB: [0..31]=ih gate frags, [32..63]=hh
    int tid = threadIdx.x, w = tid >> 6, l = tid & 63;
    int base = blockIdx.x * 64 + w * 16;
    int lr = l & 15, kb = l >> 4;
    int arow_i = base + lr;
    if (arow_i >= N_NODES) arow_i = N_NODES - 1;
    const short8* arow = (const short8*)(abf + (size_t)arow_i * D);
    const short8* hrow = (const short8*)(hbf + (size_t)arow_i * D);
    short8 afa[4], afh[4];
#pragma unroll
    for (int c = 0; c < 4; ++c) { afa[c] = arow[c * 4 + kb]; afh[c] = hrow[c * 4 + kb]; }
    float rr[8][4], zz[8][4];
    for (int p = 0; p < 3; ++p) {  // torch gate order: r, z, n
        __syncthreads();
#pragma unroll
        for (int j = 0; j < 16; ++j) {
            int ci = j * 4 + w;   // 0..63
            int fl = ci & 31;     // nt_local*4 + c, nt_local 0..7
            const unsigned short* src = (ci < 32) ? Pih : Phh;
            gload_lds16(src + ((size_t)(p * 32 + fl) * 64 + l) * 8, Bs + (size_t)ci * 512);
        }
        __syncthreads();
#pragma unroll
        for (int sub = 0; sub < 2; ++sub) {
            f32x4 ai[4] = {}, ah[4] = {};
#pragma unroll
            for (int c = 0; c < 4; ++c) {
#pragma unroll
                for (int tl = 0; tl < 4; ++tl) {
                    int fl = (sub * 4 + tl) * 4 + c;
                    short8 bi = *(const short8*)(Bs + (fl * 64 + l) * 8);
                    ai[tl] = __builtin_amdgcn_mfma_f32_16x16x32_bf16(afa[c], bi, ai[tl], 0, 0, 0);
                    short8 bh = *(const short8*)(Bs + ((32 + fl) * 64 + l) * 8);
                    ah[tl] = __builtin_amdgcn_mfma_f32_16x16x32_bf16(afh[c], bh, ah[tl], 0, 0, 0);
                }
            }
#pragma unroll
            for (int tl = 0; tl < 4; ++tl) {
                int t = sub * 4 + tl;
                int col = p * 128 + t * 16 + lr;
                float bi = bih[col], bh = bhh[col];
#pragma unroll
                for (int j = 0; j < 4; ++j) {
                    float Gi = ai[tl][j] + bi, Gh = ah[tl][j] + bh;
                    if (p == 0)      rr[t][j] = fsigmoid(Gi + Gh);
                    else if (p == 1) zz[t][j] = fsigmoid(Gi + Gh);
                    else {
                        float nn = ftanh(Gi + rr[t][j] * Gh);
                        int row = base + kb * 4 + j;
                        if (row < N_NODES) {
                            int dcol = t * 16 + lr;
                            size_t idx = (size_t)row * D + dcol;
                            float hold = bf2f_u(hbf[idx]);
                            float hn = (1.f - zz[t][j]) * nn + zz[t][j] * hold;
                            hbf[idx] = f2bf(hn);
                        }
                    }
                }
            }
        }
    }
}

// ---------------- pool phase 1: partial row-sums (bf16 h) ----------------
__global__ __launch_bounds__(256) void k_pool1(const unsigned short* __restrict__ hbf,
                                               const int* __restrict__ counts,
                                               float* __restrict__ partial) {
    __shared__ float tmp[256];
    int g = blockIdx.x / POOL_SPLIT;
    int j = blockIdx.x % POOL_SPLIT;
    int t = threadIdx.x;
    int offset = 0;
    for (int i = 0; i < g; ++i) offset += counts[i];
    int cnt = counts[g];
    int d = t & 127, half = t >> 7;
    float acc = 0.f;
    for (int r = 2 * j + half; r < cnt; r += 2 * POOL_SPLIT)
        acc += bf2f_u(hbf[(size_t)(offset + r) * D + d]);
    tmp[t] = acc;
    __syncthreads();
    if (t < D) partial[(size_t)(g * POOL_SPLIT + j) * D + t] = tmp[t] + tmp[t + 128];
}

// ---------------- pool phase 2: combine + MLP + sigmoid ----------------
__global__ __launch_bounds__(256) void k_pool2(const float* __restrict__ partial,
                                               const int* __restrict__ counts,
                                               const float* __restrict__ W1,
                                               const float* __restrict__ b1,
                                               const float* __restrict__ W2,
                                               const float* __restrict__ b2,
                                               float* __restrict__ out) {
    __shared__ float pooled[D];
    __shared__ float xh[HID];
    int g = blockIdx.x;
    int t = threadIdx.x;
    int cnt = counts[g];
    if (t < D) {
        float s = 0.f;
#pragma unroll
        for (int j = 0; j < POOL_SPLIT; ++j)
            s += partial[(size_t)(g * POOL_SPLIT + j) * D + t];
        pooled[t] = s / (float)cnt;
    }
    __syncthreads();
    float x = b1[t];
    for (int k = 0; k < D; ++k) x += pooled[k] * W1[k * HID + t];
    x = fmaxf(x, 0.f);
    xh[t] = x * W2[t];
    __syncthreads();
    for (int s = 128; s > 0; s >>= 1) {
        if (t < s) xh[t] += xh[t + s];
        __syncthreads();
    }
    if (t == 0) out[g] = 1.f / (1.f + __expf(-(xh[0] + b2[0])));
}

extern "C" void kernel_launch(void* const* d_in, const int* in_sizes, int n_in,
                              void* d_out, int out_size, void* d_ws, size_t ws_size,
                              hipStream_t stream) {
    const float* nf   = (const float*)d_in[0];
    const int* esrc   = (const int*)d_in[1];
    const int* edst   = (const int*)d_in[2];
    const int* etyp   = (const int*)d_in[3];
    const int* counts = (const int*)d_in[4];
    const float* Wmsg = (const float*)d_in[5];
    const float* bmsg = (const float*)d_in[6];   // [4][128] flat == [512] concat
    const float* Wih  = (const float*)d_in[7];
    const float* Whh  = (const float*)d_in[8];
    const float* bih  = (const float*)d_in[9];
    const float* bhh  = (const float*)d_in[10];
    const float* W1   = (const float*)d_in[11];
    const float* b1   = (const float*)d_in[12];
    const float* W2   = (const float*)d_in[13];
    const float* b2   = (const float*)d_in[14];
    float* out = (float*)d_out;

    char* ws = (char*)d_ws;
    size_t off = 0;
    auto alloc = [&](size_t bytes) {
        void* p = ws + off;
        off = (off + bytes + 255) & ~(size_t)255;
        return p;
    };
    unsigned short* hbf  = (unsigned short*)alloc((size_t)N_NODES * D * 2);
    unsigned short* abf  = (unsigned short*)alloc((size_t)N_NODES * D * 2);
    unsigned short* S    = (unsigned short*)alloc((size_t)N_NODES * 512 * 2);
    unsigned short* Pmsg = (unsigned short*)alloc(128 * 64 * 8 * 2);
    unsigned short* Pih  = (unsigned short*)alloc(24 * 4 * 64 * 8 * 2);
    unsigned short* Phh  = (unsigned short*)alloc(24 * 4 * 64 * 8 * 2);
    int* deg    = (int*)alloc((size_t)N_NODES * 4);
    unsigned* deg4 = (unsigned*)alloc((size_t)N_NODES * 16);
    int* rowptr = (int*)alloc((size_t)(N_NODES + 1) * 4);
    int* cursor = (int*)alloc((size_t)N_NODES * 4);
    int* epack  = (int*)alloc((size_t)N_EDGES * 4);
    float* partial = (float*)alloc((size_t)B_GRAPHS * POOL_SPLIT * D * 4);
    int* bsum = (int*)alloc(SCAN_B * 4);
    int* bpfx = (int*)alloc(SCAN_B * 4);

    hipMemsetAsync(deg, 0, (size_t)N_NODES * 4, stream);
    k_init_h<<<(N_NODES * D) / 256, 256, 0, stream>>>(nf, hbf);
    k_hist<<<N_EDGES / 256, 256, 0, stream>>>(edst, deg);
    k_scan1<<<SCAN_B, 256, 0, stream>>>(deg, bsum);
    k_scan2<<<1, 256, 0, stream>>>(bsum, bpfx, rowptr);
    k_scan3<<<SCAN_B, 256, 0, stream>>>(deg, bpfx, rowptr, cursor);
    k_fill<<<N_EDGES / 256, 256, 0, stream>>>(esrc, edst, etyp, cursor, epack);
    k_pack<<<320, 64, 0, stream>>>(Wmsg, Wih, Whh, Pmsg, Pih, Phh);

    int gru_blocks = (N_NODES + 63) / 64;    // 782
    int agg_blocks = (N_NODES + 3) / 4;      // 12500
    for (int s = 0; s < N_STEPS; ++s) {
        k_aggregate_s<<<agg_blocks, 256, 0, stream>>>(hbf, rowptr, epack, S, deg4);
        k_gemm_a<<<gru_blocks, 256, 0, stream>>>(S, Pmsg, deg4, bmsg, abf);
        k_gru<<<gru_blocks, 256, 0, stream>>>(abf, hbf, Pih, Phh, bih, bhh);
    }
    k_pool1<<<B_GRAPHS * POOL_SPLIT, 256, 0, stream>>>(hbf, counts, partial);
    k_pool2<<<B_GRAPHS, 256, 0, stream>>>(partial, counts, W1, b1, W2, b2, out);
}